// Round 4
// baseline (47242.789 us; speedup 1.0000x reference)
//
#include <hip/hip_runtime.h>
#include <hip/hip_bf16.h>
#include <math.h>

#define DEV __device__ __forceinline__

// ELU matching numpy: np.where(x>0, x, expm1(x)) with glibc's correctly-rounded
// expm1f. f64 expm1 + single f32 round = correctly rounded (double-rounding
// error < 2^-29 ulp).
DEV float elu_f(float v) { return v > 0.0f ? v : (float)expm1((double)v); }

constexpr int ceil_div_c(int a, int b) { return (a > 0) ? (a + b - 1) / b : -((-a) / b); }

// ---------------------------------------------------------------------------
// f32 forward conv1d, numpy/BLAS-faithful accumulation:
// per output: acc = seq FMA over (ci outer, k inner), f32, from 0; bias added
// after; matches im2col @ w.T sgemm (sequential-k FMA microkernel).
// block = 256 = 4 waves; wave -> one co; thread -> 8 consecutive outputs.
// ---------------------------------------------------------------------------
template<int K, int S, int PAD, int ACT>
__global__ __launch_bounds__(256) void conv1d_k(
    const float* __restrict__ x, const float* __restrict__ w,
    const float* __restrict__ bias, float* __restrict__ y,
    int Cin, int Cout, int Lin, int Lout)
{
  constexpr int PT = 8;
  constexpr int W  = (PT - 1) * S + K;
  constexpr int M0 = (4 - (PAD & 3)) & 3;      // (t0*S - PAD) mod 4
  constexpr int NQ = (M0 + W + 3) / 4;
  constexpr int CC = 16;
  constexpr int KP = (K + 3) & ~3;

  const int lane = threadIdx.x & 63;
  const int wv   = threadIdx.x >> 6;
  const int b    = blockIdx.z;
  const int co   = blockIdx.y * 4 + wv;
  const int t0   = (blockIdx.x * 64 + lane) * PT;

  __shared__ __align__(16) float wl[4][CC][KP];

  float acc[PT];
  #pragma unroll
  for (int g = 0; g < PT; ++g) acc[g] = 0.0f;

  const float* xb  = x + (size_t)b * Cin * Lin;
  const int start = t0 * S - PAD;
  const int vbase = start - M0;
  const bool fast = (vbase >= 0) && (vbase + 4 * NQ <= Lin);

  for (int c0 = 0; c0 < Cin; c0 += CC) {
    const int cn = (Cin - c0 < CC) ? (Cin - c0) : CC;
    __syncthreads();
    for (int i = threadIdx.x; i < 4 * cn * K; i += 256) {
      int cc  = i / (cn * K);
      int rem = i - cc * (cn * K);
      int ci  = rem / K;
      int k   = rem - ci * K;
      wl[cc][ci][k] = w[((size_t)(blockIdx.y * 4 + cc) * Cin + (c0 + ci)) * K + k];
    }
    __syncthreads();
    #pragma unroll 1
    for (int ci = 0; ci < cn; ++ci) {
      const float* xp = xb + (size_t)(c0 + ci) * Lin;
      float xr[W];
      if (fast) {
        float4 q[NQ];
        const float4* qp = (const float4*)(xp + vbase);
        #pragma unroll
        for (int j = 0; j < NQ; ++j) q[j] = qp[j];
        #pragma unroll
        for (int j = 0; j < W; ++j) xr[j] = ((const float*)q)[M0 + j];
      } else {
        #pragma unroll
        for (int j = 0; j < W; ++j) {
          int ix = start + j;
          xr[j] = (ix >= 0 && ix < Lin) ? xp[ix] : 0.0f;
        }
      }
      float wk[KP];
      const float4* wq = (const float4*)(&wl[wv][ci][0]);
      #pragma unroll
      for (int q4 = 0; q4 < KP / 4; ++q4) {
        float4 t = wq[q4];
        wk[q4*4+0] = t.x; wk[q4*4+1] = t.y; wk[q4*4+2] = t.z; wk[q4*4+3] = t.w;
      }
      #pragma unroll
      for (int k = 0; k < K; ++k) {
        const float wv_ = wk[k];
        #pragma unroll
        for (int g = 0; g < PT; ++g)
          acc[g] = fmaf(wv_, xr[g * S + k], acc[g]);   // seq (ci,k) FMA chain
      }
    }
  }

  const float bv = bias[co];
  #pragma unroll
  for (int g = 0; g < PT; ++g) {
    float v = acc[g] + bv;     // plain f32 add (no contraction possible)
    if (ACT == 1) v = elu_f(v);
    acc[g] = v;
  }
  float* yp = y + ((size_t)b * Cout + co) * Lout + t0;
  *(float4*)(yp)     = make_float4(acc[0], acc[1], acc[2], acc[3]);
  *(float4*)(yp + 4) = make_float4(acc[4], acc[5], acc[6], acc[7]);
}

// ---------------------------------------------------------------------------
// Transposed conv1d, f32 (decoder; accuracy uncritical): gather form
// ---------------------------------------------------------------------------
template<int K, int S, int PAD, int ACT>
__global__ __launch_bounds__(256) void convt1d_k(
    const float* __restrict__ x, const float* __restrict__ w,
    const float* __restrict__ bias, float* __restrict__ y,
    int Cin, int Cout, int Lin, int Lout)
{
  constexpr int PT   = 8;
  constexpr int RMIN = ceil_div_c(PAD - (K - 1), S);
  constexpr int RMAX = (PT - 1 + PAD) / S;
  constexpr int W2   = RMAX - RMIN + 1;
  constexpr int M0   = ((RMIN % 4) + 4) % 4;
  constexpr int NQ   = (M0 + W2 + 3) / 4;
  constexpr int CC   = 16;
  constexpr int KP   = (K + 3) & ~3;

  const int lane = threadIdx.x & 63;
  const int wv   = threadIdx.x >> 6;
  const int b    = blockIdx.z;
  const int co   = blockIdx.y * 4 + wv;
  const int o0   = (blockIdx.x * 64 + lane) * PT;

  __shared__ __align__(16) float wl[4][CC][KP];

  float acc[PT];
  #pragma unroll
  for (int g = 0; g < PT; ++g) acc[g] = 0.0f;

  const float* xb  = x + (size_t)b * Cin * Lin;
  const int ibase = o0 / S + RMIN;
  const int vbase = ibase - M0;
  const bool fast = (vbase >= 0) && (vbase + 4 * NQ <= Lin);

  for (int c0 = 0; c0 < Cin; c0 += CC) {
    const int cn = (Cin - c0 < CC) ? (Cin - c0) : CC;
    __syncthreads();
    for (int i = threadIdx.x; i < 4 * cn * K; i += 256) {
      int cc  = i / (cn * K);
      int rem = i - cc * (cn * K);
      int ci  = rem / K;
      int m   = rem - ci * K;
      wl[cc][ci][m] = w[((size_t)(c0 + ci) * Cout + (blockIdx.y * 4 + cc)) * K + m];
    }
    __syncthreads();
    #pragma unroll 1
    for (int ci = 0; ci < cn; ++ci) {
      const float* xp = xb + (size_t)(c0 + ci) * Lin;
      float xr[W2];
      if (fast) {
        float4 q[NQ];
        const float4* qp = (const float4*)(xp + vbase);
        #pragma unroll
        for (int j = 0; j < NQ; ++j) q[j] = qp[j];
        #pragma unroll
        for (int j = 0; j < W2; ++j) xr[j] = ((const float*)q)[M0 + j];
      } else {
        #pragma unroll
        for (int j = 0; j < W2; ++j) {
          int ix = ibase + j;
          xr[j] = (ix >= 0 && ix < Lin) ? xp[ix] : 0.0f;
        }
      }
      float wk[KP];
      const float4* wq = (const float4*)(&wl[wv][ci][0]);
      #pragma unroll
      for (int q4 = 0; q4 < KP / 4; ++q4) {
        float4 t = wq[q4];
        wk[q4*4+0] = t.x; wk[q4*4+1] = t.y; wk[q4*4+2] = t.z; wk[q4*4+3] = t.w;
      }
      #pragma unroll
      for (int m = 0; m < K; ++m) {
        const float wv_ = wk[m];
        #pragma unroll
        for (int g = 0; g < PT; ++g) {
          if (((g + PAD - m) % S) == 0) {
            acc[g] = fmaf(wv_, xr[(g + PAD - m) / S - RMIN], acc[g]);
          }
        }
      }
    }
  }

  const float bv = bias[co];
  #pragma unroll
  for (int g = 0; g < PT; ++g) {
    float v = acc[g] + bv;
    if (ACT == 1) v = elu_f(v);
    acc[g] = v;
  }
  float* yp = y + ((size_t)b * Cout + co) * Lout + o0;
  *(float4*)(yp)     = make_float4(acc[0], acc[1], acc[2], acc[3]);
  *(float4*)(yp + 4) = make_float4(acc[4], acc[5], acc[6], acc[7]);
}

// ---------------------------------------------------------------------------
// Final decoder layer: convt K15 S1 P7, Cin=64, Cout=1, tanh -> recon (8,65536)
// ---------------------------------------------------------------------------
__global__ __launch_bounds__(256) void convt_final_k(
    const float* __restrict__ x, const float* __restrict__ w,
    const float* __restrict__ bias, float* __restrict__ y)
{
  constexpr int K = 15, PAD = 7, PT = 8, Cin = 64, Lin = 65536;
  constexpr int RMIN = PAD - (K - 1);             // -7
  constexpr int W2   = (PT - 1 + PAD) - RMIN + 1; // 22
  constexpr int M0   = ((RMIN % 4) + 4) % 4;      // 1
  constexpr int NQ   = (M0 + W2 + 3) / 4;         // 6
  __shared__ __align__(16) float wl[Cin][16];
  for (int i = threadIdx.x; i < Cin * K; i += 256) wl[i / K][i % K] = w[i];
  __syncthreads();
  const int b  = blockIdx.z;
  const int o0 = (blockIdx.x * 256 + threadIdx.x) * PT;
  float acc[PT];
  #pragma unroll
  for (int g = 0; g < PT; ++g) acc[g] = 0.0f;
  const int ibase = o0 + RMIN;
  const int vbase = ibase - M0;
  const bool fast = (vbase >= 0) && (vbase + 4 * NQ <= Lin);
  #pragma unroll 1
  for (int ci = 0; ci < Cin; ++ci) {
    const float* xp = x + ((size_t)b * Cin + ci) * Lin;
    float xr[W2];
    if (fast) {
      float4 q[NQ];
      const float4* qp = (const float4*)(xp + vbase);
      #pragma unroll
      for (int j = 0; j < NQ; ++j) q[j] = qp[j];
      #pragma unroll
      for (int j = 0; j < W2; ++j) xr[j] = ((const float*)q)[M0 + j];
    } else {
      #pragma unroll
      for (int j = 0; j < W2; ++j) {
        int ix = ibase + j;
        xr[j] = (ix >= 0 && ix < Lin) ? xp[ix] : 0.0f;
      }
    }
    float wk[16];
    const float4* wq = (const float4*)(&wl[ci][0]);
    #pragma unroll
    for (int q4 = 0; q4 < 4; ++q4) {
      float4 t = wq[q4];
      wk[q4*4+0] = t.x; wk[q4*4+1] = t.y; wk[q4*4+2] = t.z; wk[q4*4+3] = t.w;
    }
    #pragma unroll
    for (int m = 0; m < K; ++m) {
      #pragma unroll
      for (int g = 0; g < PT; ++g)
        acc[g] = fmaf(wk[m], xr[g + PAD - m - RMIN], acc[g]);
    }
  }
  const float bv = bias[0];
  float* yp = y + (size_t)b * 65536 + o0;
  #pragma unroll
  for (int g = 0; g < PT; ++g) acc[g] = tanhf(acc[g] + bv);
  *(float4*)(yp)     = make_float4(acc[0], acc[1], acc[2], acc[3]);
  *(float4*)(yp + 4) = make_float4(acc[4], acc[5], acc[6], acc[7]);
}

// ---------------------------------------------------------------------------
// Batched 2D transpose: in (B, R, S) -> out (B, S, R). R,S multiples of 32.
// ---------------------------------------------------------------------------
__global__ __launch_bounds__(256) void transpose_k(
    const float* __restrict__ in, float* __restrict__ out, int R, int S_)
{
  __shared__ float tile[32][33];
  const int b  = blockIdx.z;
  const int r0 = blockIdx.y * 32;
  const int s0 = blockIdx.x * 32;
  const float* ib = in + (size_t)b * R * S_;
  float* ob = out + (size_t)b * R * S_;
  const int tx = threadIdx.x, ty = threadIdx.y;
  #pragma unroll
  for (int i = 0; i < 32; i += 8)
    tile[ty + i][tx] = ib[(size_t)(r0 + ty + i) * S_ + s0 + tx];
  __syncthreads();
  #pragma unroll
  for (int i = 0; i < 32; i += 8)
    ob[(size_t)(s0 + ty + i) * R + r0 + tx] = tile[tx][ty + i];
}

// ---------------------------------------------------------------------------
// numpy-pairwise-identical f32 sum of squares over 512 contiguous floats.
// 512 -> 256+256 -> (128+128)+(128+128); each 128-block: 8 accumulators
// stride 8, combine ((r0+r1)+(r2+r3))+((r4+r5)+(r6+r7)).
// __fadd_rn/__fmul_rn block FMA contraction (numpy squares first, then sums).
// ---------------------------------------------------------------------------
DEV float np_sumsq_128(const float* a) {
  float r[8];
  #pragma unroll
  for (int j = 0; j < 8; ++j) r[j] = __fmul_rn(a[j], a[j]);
  #pragma unroll
  for (int i = 8; i < 128; i += 8) {
    #pragma unroll
    for (int j = 0; j < 8; ++j)
      r[j] = __fadd_rn(r[j], __fmul_rn(a[i + j], a[i + j]));
  }
  float s01 = __fadd_rn(r[0], r[1]), s23 = __fadd_rn(r[2], r[3]);
  float s45 = __fadd_rn(r[4], r[5]), s67 = __fadd_rn(r[6], r[7]);
  return __fadd_rn(__fadd_rn(s01, s23), __fadd_rn(s45, s67));
}
DEV float np_sumsq_512(const float* a) {
  float s0 = np_sumsq_128(a);
  float s1 = np_sumsq_128(a + 128);
  float s2 = np_sumsq_128(a + 256);
  float s3 = np_sumsq_128(a + 384);
  return __fadd_rn(__fadd_rn(s0, s1), __fadd_rn(s2, s3));
}

__global__ __launch_bounds__(256) void rowsumsq_k(
    const float* __restrict__ in, float* __restrict__ out, int nrows)
{
  const int r = blockIdx.x * 256 + threadIdx.x;
  if (r >= nrows) return;
  out[r] = np_sumsq_512(in + (size_t)r * 512);
}

// ---------------------------------------------------------------------------
// VQ, numpy-f32-faithful: 8 rows/block, 4 codes/thread (k = tid + 256*j).
// dot: sequential-k f32 FMA (sgemm microkernel order).
// dist = fl32( fl32(t1[row] + cn[k]) - 2*dot )  -- exact np expression shape.
// argmin: strict less, tie -> lowest index (np first-occurrence).
// ---------------------------------------------------------------------------
__global__ __launch_bounds__(256) void vq_k(
    const float* __restrict__ embT, const float* __restrict__ cb,
    const float* __restrict__ t1, const float* __restrict__ cnorm,
    float* __restrict__ qout, float* __restrict__ codes, float* __restrict__ pc)
{
  __shared__ __align__(16) float xs[8][512];
  __shared__ float rv[4][8];
  __shared__ int   ri[4][8];
  __shared__ int   bidx[8];
  __shared__ float cred[4];

  const int tid  = threadIdx.x;
  const int row0 = blockIdx.x * 8;

  for (int i = tid * 4; i < 4096; i += 1024)
    *(float4*)((float*)xs + i) = *(const float4*)(embT + (size_t)row0 * 512 + i);
  __syncthreads();

  float acc[4][8];
  #pragma unroll
  for (int j = 0; j < 4; ++j)
    #pragma unroll
    for (int r = 0; r < 8; ++r) acc[j][r] = 0.0f;

  const float* cbp = cb + (size_t)tid * 512;
  #pragma unroll 1
  for (int d0 = 0; d0 < 512; d0 += 4) {
    float4 xv[8];
    #pragma unroll
    for (int r = 0; r < 8; ++r) xv[r] = *(const float4*)&xs[r][d0];
    #pragma unroll
    for (int j = 0; j < 4; ++j) {
      float4 cv = *(const float4*)(cbp + (size_t)j * 256 * 512 + d0);
      #pragma unroll
      for (int r = 0; r < 8; ++r) {
        acc[j][r] = fmaf(cv.x, xv[r].x, acc[j][r]);
        acc[j][r] = fmaf(cv.y, xv[r].y, acc[j][r]);
        acc[j][r] = fmaf(cv.z, xv[r].z, acc[j][r]);
        acc[j][r] = fmaf(cv.w, xv[r].w, acc[j][r]);
      }
    }
  }

  float cnj[4];
  #pragma unroll
  for (int j = 0; j < 4; ++j) cnj[j] = cnorm[tid + 256 * j];
  float t1r[8];
  #pragma unroll
  for (int r = 0; r < 8; ++r) t1r[r] = t1[row0 + r];

  const int lane = tid & 63, wv = tid >> 6;
  #pragma unroll 1
  for (int r = 0; r < 8; ++r) {
    float bv = 0.0f; int bi = 0;
    #pragma unroll
    for (int j = 0; j < 4; ++j) {
      float dv = __fsub_rn(__fadd_rn(t1r[r], cnj[j]), __fmul_rn(2.0f, acc[j][r]));
      int ki = tid + 256 * j;
      if (j == 0 || dv < bv || (dv == bv && ki < bi)) { bv = dv; bi = ki; }
    }
    #pragma unroll
    for (int off = 32; off; off >>= 1) {
      float ov = __shfl_xor(bv, off);
      int   oi = __shfl_xor(bi, off);
      if (ov < bv || (ov == bv && oi < bi)) { bv = ov; bi = oi; }
    }
    if (lane == 0) { rv[wv][r] = bv; ri[wv][r] = bi; }
  }
  __syncthreads();
  if (tid < 8) {
    float bv = rv[0][tid]; int bi = ri[0][tid];
    #pragma unroll
    for (int wq = 1; wq < 4; ++wq) {
      float ov = rv[wq][tid]; int oi = ri[wq][tid];
      if (ov < bv || (ov == bv && oi < bi)) { bv = ov; bi = oi; }
    }
    bidx[tid] = bi;
    codes[row0 + tid] = (float)bi;
  }
  __syncthreads();

  float csum = 0.0f;
  for (int i = tid * 4; i < 4096; i += 1024) {
    int r = i >> 9, d = i & 511;
    float4 qv = *(const float4*)(cb + (size_t)bidx[r] * 512 + d);
    *(float4*)(qout + (size_t)(row0 + r) * 512 + d) = qv;
    float dx = qv.x - xs[r][d],     dy = qv.y - xs[r][d + 1];
    float dz = qv.z - xs[r][d + 2], dw = qv.w - xs[r][d + 3];
    csum += dx * dx + dy * dy + dz * dz + dw * dw;
  }
  #pragma unroll
  for (int off = 32; off; off >>= 1) csum += __shfl_xor(csum, off);
  if (lane == 0) cred[wv] = csum;
  __syncthreads();
  if (tid == 0) pc[blockIdx.x] = cred[0] + cred[1] + cred[2] + cred[3];
}

// ---------------------------------------------------------------------------
// recon |diff| partial reduce: 256 blocks over 524288 elems
// ---------------------------------------------------------------------------
__global__ __launch_bounds__(256) void absdiff_part_k(
    const float* __restrict__ a, const float* __restrict__ b, float* __restrict__ pr)
{
  __shared__ float cred[4];
  const int tid  = threadIdx.x;
  const int base = blockIdx.x * 2048;
  float s = 0.0f;
  for (int i = tid * 4; i < 2048; i += 1024) {
    float4 x = *(const float4*)(a + base + i);
    float4 y = *(const float4*)(b + base + i);
    s += fabsf(x.x - y.x) + fabsf(x.y - y.y) + fabsf(x.z - y.z) + fabsf(x.w - y.w);
  }
  #pragma unroll
  for (int off = 32; off; off >>= 1) s += __shfl_xor(s, off);
  const int lane = tid & 63, wv = tid >> 6;
  if (lane == 0) cred[wv] = s;
  __syncthreads();
  if (tid == 0) pr[blockIdx.x] = cred[0] + cred[1] + cred[2] + cred[3];
}

// ---------------------------------------------------------------------------
// Final scalar losses (single block, deterministic)
// ---------------------------------------------------------------------------
__global__ __launch_bounds__(256) void finalize_k(
    const float* __restrict__ pc, const float* __restrict__ pr, float* __restrict__ outp)
{
  __shared__ float red[4];
  const int tid = threadIdx.x;
  const int lane = tid & 63, wv = tid >> 6;

  float s = 0.0f;
  for (int i = tid; i < 8192; i += 256) s += pc[i];
  #pragma unroll
  for (int off = 32; off; off >>= 1) s += __shfl_xor(s, off);
  if (lane == 0) red[wv] = s;
  __syncthreads();
  if (tid == 0) outp[0] = 0.25f * (red[0] + red[1] + red[2] + red[3]) / 33554432.0f;
  __syncthreads();

  float s2 = 0.0f;
  if (tid < 64) {
    for (int i = tid; i < 256; i += 64) s2 += pr[i];
    #pragma unroll
    for (int off = 32; off; off >>= 1) s2 += __shfl_xor(s2, off);
    if (tid == 0) outp[1] = s2 / 524288.0f;
  }
}

// ---------------------------------------------------------------------------
extern "C" void kernel_launch(void* const* d_in, const int* in_sizes, int n_in,
                              void* d_out, int out_size, void* d_ws, size_t ws_size,
                              hipStream_t stream) {
  const float* wave = (const float*)d_in[0];
  const float* e1w = (const float*)d_in[1];  const float* e1b = (const float*)d_in[2];
  const float* e2w = (const float*)d_in[3];  const float* e2b = (const float*)d_in[4];
  const float* e3w = (const float*)d_in[5];  const float* e3b = (const float*)d_in[6];
  const float* e4w = (const float*)d_in[7];  const float* e4b = (const float*)d_in[8];
  const float* e5w = (const float*)d_in[9];  const float* e5b = (const float*)d_in[10];
  const float* cb  = (const float*)d_in[11];
  const float* d1w = (const float*)d_in[12]; const float* d1b = (const float*)d_in[13];
  const float* d2w = (const float*)d_in[14]; const float* d2b = (const float*)d_in[15];
  const float* d3w = (const float*)d_in[16]; const float* d3b = (const float*)d_in[17];
  const float* d4w = (const float*)d_in[18]; const float* d4b = (const float*)d_in[19];
  const float* d5w = (const float*)d_in[20]; const float* d5b = (const float*)d_in[21];

  float* out = (float*)d_out;
  float* recon  = out;                   // (8, 65536)
  float* qout   = out + 524288;          // (8, 8192, 512)
  float* codes  = out + 34078720;        // (8, 8192) as float
  float* losses = out + 34144256;        // [commitment, recon]

  float* A   = (float*)d_ws;             // 33554432 floats
  float* Bb  = A + 33554432;             // 33554432 floats
  float* t1  = Bb + 33554432;            // 65536
  float* cn  = t1 + 65536;               // 1024
  float* pc  = cn + 1024;                // 8192
  float* pr  = pc + 8192;                // 256

  dim3 blk(256);

  // ---- encoder (f32, numpy-faithful) ----
  conv1d_k<15,1,7,1><<<dim3(128, 16, 8), blk, 0, stream>>>(wave, e1w, e1b, A,   1,  64, 65536, 65536);
  conv1d_k<15,2,7,1><<<dim3( 64, 32, 8), blk, 0, stream>>>(A,    e2w, e2b, Bb, 64, 128, 65536, 32768);
  conv1d_k<15,2,7,1><<<dim3( 32, 64, 8), blk, 0, stream>>>(Bb,   e3w, e3b, A, 128, 256, 32768, 16384);
  conv1d_k<15,2,7,1><<<dim3( 16,128, 8), blk, 0, stream>>>(A,    e4w, e4b, Bb,256, 512, 16384,  8192);
  conv1d_k< 7,1,3,0><<<dim3( 16,128, 8), blk, 0, stream>>>(Bb,   e5w, e5b, A, 512, 512,  8192,  8192);

  // ---- VQ (f32 numpy expression) ----
  transpose_k<<<dim3(256, 16, 8), dim3(32, 8), 0, stream>>>(A, Bb, 512, 8192);   // emb -> embT (B,T,D)
  rowsumsq_k<<<dim3(256), blk, 0, stream>>>(Bb, t1, 65536);
  rowsumsq_k<<<dim3(4),   blk, 0, stream>>>(cb, cn, 1024);
  vq_k<<<dim3(8192), blk, 0, stream>>>(Bb, cb, t1, cn, qout, codes, pc);
  transpose_k<<<dim3(16, 256, 8), dim3(32, 8), 0, stream>>>(qout, A, 8192, 512); // q -> (B,D,T)

  // ---- decoder (f32) ----
  convt1d_k< 7,1,3,1><<<dim3( 16,128, 8), blk, 0, stream>>>(A,  d1w, d1b, Bb, 512, 512,  8192,  8192);
  convt1d_k<15,2,7,1><<<dim3( 32, 64, 8), blk, 0, stream>>>(Bb, d2w, d2b, A,  512, 256,  8192, 16384);
  convt1d_k<15,2,7,1><<<dim3( 64, 32, 8), blk, 0, stream>>>(A,  d3w, d3b, Bb, 256, 128, 16384, 32768);
  convt1d_k<15,2,7,1><<<dim3(128, 16, 8), blk, 0, stream>>>(Bb, d4w, d4b, A,  128,  64, 32768, 65536);
  convt_final_k<<<dim3(32, 1, 8), blk, 0, stream>>>(A, d5w, d5b, recon);

  // ---- losses ----
  absdiff_part_k<<<dim3(256), blk, 0, stream>>>(recon, wave, pr);
  finalize_k<<<dim3(1), blk, 0, stream>>>(pc, pr, losses);
}

// Round 5
// 24360.542 us; speedup vs baseline: 1.9393x; 1.9393x over previous
//
#include <hip/hip_runtime.h>
#include <hip/hip_bf16.h>
#include <math.h>

#define DEV __device__ __forceinline__

// ELU matching numpy: f64 expm1 + single f32 round == correctly-rounded expm1f.
DEV float elu_f(float v) { return v > 0.0f ? v : (float)expm1((double)v); }

constexpr int ceil_div_c(int a, int b) { return (a > 0) ? (a + b - 1) / b : -((-a) / b); }

// ---------------------------------------------------------------------------
// f32 forward conv1d, numpy/BLAS-faithful accumulation.
// block = 256 = 4 waves; wave -> 4 co (16 co/block); thread -> 8 outputs.
// Per output the FMA chain is sequential (ci outer, k inner) — bit-identical
// to the round-4 passing kernel (required for exact VQ argmin downstream).
// ---------------------------------------------------------------------------
template<int K, int S, int PAD, int ACT>
__global__ __launch_bounds__(256) void conv1d_k(
    const float* __restrict__ x, const float* __restrict__ w,
    const float* __restrict__ bias, float* __restrict__ y,
    int Cin, int Cout, int Lin, int Lout)
{
  constexpr int PT = 8;
  constexpr int W  = (PT - 1) * S + K;
  constexpr int M0 = (4 - (PAD & 3)) & 3;      // (t0*S - PAD) mod 4
  constexpr int NQ = (M0 + W + 3) / 4;
  constexpr int CC = 16;
  constexpr int KP = (K + 3) & ~3;

  const int lane = threadIdx.x & 63;
  const int wv   = threadIdx.x >> 6;
  const int b    = blockIdx.z;
  const int cob  = blockIdx.y * 16;            // block's first co
  const int t0   = (blockIdx.x * 64 + lane) * PT;

  __shared__ __align__(16) float wl[16][CC][KP];

  float acc[4][PT];
  #pragma unroll
  for (int cc = 0; cc < 4; ++cc)
    #pragma unroll
    for (int g = 0; g < PT; ++g) acc[cc][g] = 0.0f;

  const float* xb  = x + (size_t)b * Cin * Lin;
  const int start = t0 * S - PAD;
  const int vbase = start - M0;
  const bool fast = (vbase >= 0) && (vbase + 4 * NQ <= Lin);

  for (int c0 = 0; c0 < Cin; c0 += CC) {
    const int cn = (Cin - c0 < CC) ? (Cin - c0) : CC;
    __syncthreads();
    for (int i = threadIdx.x; i < 16 * cn * K; i += 256) {
      int cc  = i / (cn * K);
      int rem = i - cc * (cn * K);
      int ci  = rem / K;
      int k   = rem - ci * K;
      wl[cc][ci][k] = w[((size_t)(cob + cc) * Cin + (c0 + ci)) * K + k];
    }
    __syncthreads();
    #pragma unroll 1
    for (int ci = 0; ci < cn; ++ci) {
      const float* xp = xb + (size_t)(c0 + ci) * Lin;
      float xr[W];
      if (fast) {
        float4 q[NQ];
        const float4* qp = (const float4*)(xp + vbase);
        #pragma unroll
        for (int j = 0; j < NQ; ++j) q[j] = qp[j];
        #pragma unroll
        for (int j = 0; j < W; ++j) xr[j] = ((const float*)q)[M0 + j];
      } else {
        #pragma unroll
        for (int j = 0; j < W; ++j) {
          int ix = start + j;
          xr[j] = (ix >= 0 && ix < Lin) ? xp[ix] : 0.0f;
        }
      }
      #pragma unroll
      for (int cc = 0; cc < 4; ++cc) {
        float wk[KP];
        const float4* wq = (const float4*)(&wl[wv * 4 + cc][ci][0]);
        #pragma unroll
        for (int q4 = 0; q4 < KP / 4; ++q4) {
          float4 t = wq[q4];
          wk[q4*4+0] = t.x; wk[q4*4+1] = t.y; wk[q4*4+2] = t.z; wk[q4*4+3] = t.w;
        }
        #pragma unroll
        for (int k = 0; k < K; ++k) {
          const float wv_ = wk[k];
          #pragma unroll
          for (int g = 0; g < PT; ++g)
            acc[cc][g] = fmaf(wv_, xr[g * S + k], acc[cc][g]);  // seq (ci,k)
        }
      }
    }
  }

  #pragma unroll
  for (int cc = 0; cc < 4; ++cc) {
    const int co = cob + wv * 4 + cc;
    const float bv = bias[co];
    float res[PT];
    #pragma unroll
    for (int g = 0; g < PT; ++g) {
      float v = acc[cc][g] + bv;
      if (ACT == 1) v = elu_f(v);
      res[g] = v;
    }
    float* yp = y + ((size_t)b * Cout + co) * Lout + t0;
    *(float4*)(yp)     = make_float4(res[0], res[1], res[2], res[3]);
    *(float4*)(yp + 4) = make_float4(res[4], res[5], res[6], res[7]);
  }
}

// ---------------------------------------------------------------------------
// Transposed conv1d, f32 (decoder): gather form, 4 co per wave (16/block).
// ---------------------------------------------------------------------------
template<int K, int S, int PAD, int ACT>
__global__ __launch_bounds__(256) void convt1d_k(
    const float* __restrict__ x, const float* __restrict__ w,
    const float* __restrict__ bias, float* __restrict__ y,
    int Cin, int Cout, int Lin, int Lout)
{
  constexpr int PT   = 8;
  constexpr int RMIN = ceil_div_c(PAD - (K - 1), S);
  constexpr int RMAX = (PT - 1 + PAD) / S;
  constexpr int W2   = RMAX - RMIN + 1;
  constexpr int M0   = ((RMIN % 4) + 4) % 4;
  constexpr int NQ   = (M0 + W2 + 3) / 4;
  constexpr int CC   = 16;
  constexpr int KP   = (K + 3) & ~3;

  const int lane = threadIdx.x & 63;
  const int wv   = threadIdx.x >> 6;
  const int b    = blockIdx.z;
  const int cob  = blockIdx.y * 16;
  const int o0   = (blockIdx.x * 64 + lane) * PT;

  __shared__ __align__(16) float wl[16][CC][KP];

  float acc[4][PT];
  #pragma unroll
  for (int cc = 0; cc < 4; ++cc)
    #pragma unroll
    for (int g = 0; g < PT; ++g) acc[cc][g] = 0.0f;

  const float* xb  = x + (size_t)b * Cin * Lin;
  const int ibase = o0 / S + RMIN;
  const int vbase = ibase - M0;
  const bool fast = (vbase >= 0) && (vbase + 4 * NQ <= Lin);

  for (int c0 = 0; c0 < Cin; c0 += CC) {
    const int cn = (Cin - c0 < CC) ? (Cin - c0) : CC;
    __syncthreads();
    for (int i = threadIdx.x; i < 16 * cn * K; i += 256) {
      int cc  = i / (cn * K);
      int rem = i - cc * (cn * K);
      int ci  = rem / K;
      int m   = rem - ci * K;
      wl[cc][ci][m] = w[((size_t)(c0 + ci) * Cout + (cob + cc)) * K + m];
    }
    __syncthreads();
    #pragma unroll 1
    for (int ci = 0; ci < cn; ++ci) {
      const float* xp = xb + (size_t)(c0 + ci) * Lin;
      float xr[W2];
      if (fast) {
        float4 q[NQ];
        const float4* qp = (const float4*)(xp + vbase);
        #pragma unroll
        for (int j = 0; j < NQ; ++j) q[j] = qp[j];
        #pragma unroll
        for (int j = 0; j < W2; ++j) xr[j] = ((const float*)q)[M0 + j];
      } else {
        #pragma unroll
        for (int j = 0; j < W2; ++j) {
          int ix = ibase + j;
          xr[j] = (ix >= 0 && ix < Lin) ? xp[ix] : 0.0f;
        }
      }
      #pragma unroll
      for (int cc = 0; cc < 4; ++cc) {
        float wk[KP];
        const float4* wq = (const float4*)(&wl[wv * 4 + cc][ci][0]);
        #pragma unroll
        for (int q4 = 0; q4 < KP / 4; ++q4) {
          float4 t = wq[q4];
          wk[q4*4+0] = t.x; wk[q4*4+1] = t.y; wk[q4*4+2] = t.z; wk[q4*4+3] = t.w;
        }
        #pragma unroll
        for (int m = 0; m < K; ++m) {
          const float wv_ = wk[m];
          #pragma unroll
          for (int g = 0; g < PT; ++g) {
            if (((g + PAD - m) % S) == 0) {
              acc[cc][g] = fmaf(wv_, xr[(g + PAD - m) / S - RMIN], acc[cc][g]);
            }
          }
        }
      }
    }
  }

  #pragma unroll
  for (int cc = 0; cc < 4; ++cc) {
    const int co = cob + wv * 4 + cc;
    const float bv = bias[co];
    float res[PT];
    #pragma unroll
    for (int g = 0; g < PT; ++g) {
      float v = acc[cc][g] + bv;
      if (ACT == 1) v = elu_f(v);
      res[g] = v;
    }
    float* yp = y + ((size_t)b * Cout + co) * Lout + o0;
    *(float4*)(yp)     = make_float4(res[0], res[1], res[2], res[3]);
    *(float4*)(yp + 4) = make_float4(res[4], res[5], res[6], res[7]);
  }
}

// ---------------------------------------------------------------------------
// Final decoder layer: convt K15 S1 P7, Cin=64, Cout=1, tanh -> recon (8,65536)
// ---------------------------------------------------------------------------
__global__ __launch_bounds__(256) void convt_final_k(
    const float* __restrict__ x, const float* __restrict__ w,
    const float* __restrict__ bias, float* __restrict__ y)
{
  constexpr int K = 15, PAD = 7, PT = 8, Cin = 64, Lin = 65536;
  constexpr int RMIN = PAD - (K - 1);             // -7
  constexpr int W2   = (PT - 1 + PAD) - RMIN + 1; // 22
  constexpr int M0   = ((RMIN % 4) + 4) % 4;      // 1
  constexpr int NQ   = (M0 + W2 + 3) / 4;         // 6
  __shared__ __align__(16) float wl[Cin][16];
  for (int i = threadIdx.x; i < Cin * K; i += 256) wl[i / K][i % K] = w[i];
  __syncthreads();
  const int b  = blockIdx.z;
  const int o0 = (blockIdx.x * 256 + threadIdx.x) * PT;
  float acc[PT];
  #pragma unroll
  for (int g = 0; g < PT; ++g) acc[g] = 0.0f;
  const int ibase = o0 + RMIN;
  const int vbase = ibase - M0;
  const bool fast = (vbase >= 0) && (vbase + 4 * NQ <= Lin);
  #pragma unroll 1
  for (int ci = 0; ci < Cin; ++ci) {
    const float* xp = x + ((size_t)b * Cin + ci) * Lin;
    float xr[W2];
    if (fast) {
      float4 q[NQ];
      const float4* qp = (const float4*)(xp + vbase);
      #pragma unroll
      for (int j = 0; j < NQ; ++j) q[j] = qp[j];
      #pragma unroll
      for (int j = 0; j < W2; ++j) xr[j] = ((const float*)q)[M0 + j];
    } else {
      #pragma unroll
      for (int j = 0; j < W2; ++j) {
        int ix = ibase + j;
        xr[j] = (ix >= 0 && ix < Lin) ? xp[ix] : 0.0f;
      }
    }
    float wk[16];
    const float4* wq = (const float4*)(&wl[ci][0]);
    #pragma unroll
    for (int q4 = 0; q4 < 4; ++q4) {
      float4 t = wq[q4];
      wk[q4*4+0] = t.x; wk[q4*4+1] = t.y; wk[q4*4+2] = t.z; wk[q4*4+3] = t.w;
    }
    #pragma unroll
    for (int m = 0; m < K; ++m) {
      #pragma unroll
      for (int g = 0; g < PT; ++g)
        acc[g] = fmaf(wk[m], xr[g + PAD - m - RMIN], acc[g]);
    }
  }
  const float bv = bias[0];
  float* yp = y + (size_t)b * 65536 + o0;
  #pragma unroll
  for (int g = 0; g < PT; ++g) acc[g] = tanhf(acc[g] + bv);
  *(float4*)(yp)     = make_float4(acc[0], acc[1], acc[2], acc[3]);
  *(float4*)(yp + 4) = make_float4(acc[4], acc[5], acc[6], acc[7]);
}

// ---------------------------------------------------------------------------
// Batched 2D transpose: in (B, R, S) -> out (B, S, R). R,S multiples of 32.
// ---------------------------------------------------------------------------
__global__ __launch_bounds__(256) void transpose_k(
    const float* __restrict__ in, float* __restrict__ out, int R, int S_)
{
  __shared__ float tile[32][33];
  const int b  = blockIdx.z;
  const int r0 = blockIdx.y * 32;
  const int s0 = blockIdx.x * 32;
  const float* ib = in + (size_t)b * R * S_;
  float* ob = out + (size_t)b * R * S_;
  const int tx = threadIdx.x, ty = threadIdx.y;
  #pragma unroll
  for (int i = 0; i < 32; i += 8)
    tile[ty + i][tx] = ib[(size_t)(r0 + ty + i) * S_ + s0 + tx];
  __syncthreads();
  #pragma unroll
  for (int i = 0; i < 32; i += 8)
    ob[(size_t)(s0 + ty + i) * R + r0 + tx] = tile[tx][ty + i];
}

// ---------------------------------------------------------------------------
// numpy-pairwise-identical f32 sum of squares over 512 contiguous floats.
// ---------------------------------------------------------------------------
DEV float np_sumsq_128(const float* a) {
  float r[8];
  #pragma unroll
  for (int j = 0; j < 8; ++j) r[j] = __fmul_rn(a[j], a[j]);
  #pragma unroll
  for (int i = 8; i < 128; i += 8) {
    #pragma unroll
    for (int j = 0; j < 8; ++j)
      r[j] = __fadd_rn(r[j], __fmul_rn(a[i + j], a[i + j]));
  }
  float s01 = __fadd_rn(r[0], r[1]), s23 = __fadd_rn(r[2], r[3]);
  float s45 = __fadd_rn(r[4], r[5]), s67 = __fadd_rn(r[6], r[7]);
  return __fadd_rn(__fadd_rn(s01, s23), __fadd_rn(s45, s67));
}
DEV float np_sumsq_512(const float* a) {
  float s0 = np_sumsq_128(a);
  float s1 = np_sumsq_128(a + 128);
  float s2 = np_sumsq_128(a + 256);
  float s3 = np_sumsq_128(a + 384);
  return __fadd_rn(__fadd_rn(s0, s1), __fadd_rn(s2, s3));
}

__global__ __launch_bounds__(256) void rowsumsq_k(
    const float* __restrict__ in, float* __restrict__ out, int nrows)
{
  const int r = blockIdx.x * 256 + threadIdx.x;
  if (r >= nrows) return;
  out[r] = np_sumsq_512(in + (size_t)r * 512);
}

// ---------------------------------------------------------------------------
// VQ, numpy-f32-faithful: 8 rows/block, 4 codes/thread (k = tid + 256*j).
// dist = fl32( fl32(t1[row] + cn[k]) - 2*dot ), argmin tie -> lowest index.
// ---------------------------------------------------------------------------
__global__ __launch_bounds__(256) void vq_k(
    const float* __restrict__ embT, const float* __restrict__ cb,
    const float* __restrict__ t1, const float* __restrict__ cnorm,
    float* __restrict__ qout, float* __restrict__ codes, float* __restrict__ pc)
{
  __shared__ __align__(16) float xs[8][512];
  __shared__ float rv[4][8];
  __shared__ int   ri[4][8];
  __shared__ int   bidx[8];
  __shared__ float cred[4];

  const int tid  = threadIdx.x;
  const int row0 = blockIdx.x * 8;

  for (int i = tid * 4; i < 4096; i += 1024)
    *(float4*)((float*)xs + i) = *(const float4*)(embT + (size_t)row0 * 512 + i);
  __syncthreads();

  float acc[4][8];
  #pragma unroll
  for (int j = 0; j < 4; ++j)
    #pragma unroll
    for (int r = 0; r < 8; ++r) acc[j][r] = 0.0f;

  const float* cbp = cb + (size_t)tid * 512;
  #pragma unroll 1
  for (int d0 = 0; d0 < 512; d0 += 4) {
    float4 xv[8];
    #pragma unroll
    for (int r = 0; r < 8; ++r) xv[r] = *(const float4*)&xs[r][d0];
    #pragma unroll
    for (int j = 0; j < 4; ++j) {
      float4 cv = *(const float4*)(cbp + (size_t)j * 256 * 512 + d0);
      #pragma unroll
      for (int r = 0; r < 8; ++r) {
        acc[j][r] = fmaf(cv.x, xv[r].x, acc[j][r]);
        acc[j][r] = fmaf(cv.y, xv[r].y, acc[j][r]);
        acc[j][r] = fmaf(cv.z, xv[r].z, acc[j][r]);
        acc[j][r] = fmaf(cv.w, xv[r].w, acc[j][r]);
      }
    }
  }

  float cnj[4];
  #pragma unroll
  for (int j = 0; j < 4; ++j) cnj[j] = cnorm[tid + 256 * j];
  float t1r[8];
  #pragma unroll
  for (int r = 0; r < 8; ++r) t1r[r] = t1[row0 + r];

  const int lane = tid & 63, wv = tid >> 6;
  #pragma unroll 1
  for (int r = 0; r < 8; ++r) {
    float bv = 0.0f; int bi = 0;
    #pragma unroll
    for (int j = 0; j < 4; ++j) {
      float dv = __fsub_rn(__fadd_rn(t1r[r], cnj[j]), __fmul_rn(2.0f, acc[j][r]));
      int ki = tid + 256 * j;
      if (j == 0 || dv < bv || (dv == bv && ki < bi)) { bv = dv; bi = ki; }
    }
    #pragma unroll
    for (int off = 32; off; off >>= 1) {
      float ov = __shfl_xor(bv, off);
      int   oi = __shfl_xor(bi, off);
      if (ov < bv || (ov == bv && oi < bi)) { bv = ov; bi = oi; }
    }
    if (lane == 0) { rv[wv][r] = bv; ri[wv][r] = bi; }
  }
  __syncthreads();
  if (tid < 8) {
    float bv = rv[0][tid]; int bi = ri[0][tid];
    #pragma unroll
    for (int wq = 1; wq < 4; ++wq) {
      float ov = rv[wq][tid]; int oi = ri[wq][tid];
      if (ov < bv || (ov == bv && oi < bi)) { bv = ov; bi = oi; }
    }
    bidx[tid] = bi;
    codes[row0 + tid] = (float)bi;
  }
  __syncthreads();

  float csum = 0.0f;
  for (int i = tid * 4; i < 4096; i += 1024) {
    int r = i >> 9, d = i & 511;
    float4 qv = *(const float4*)(cb + (size_t)bidx[r] * 512 + d);
    *(float4*)(qout + (size_t)(row0 + r) * 512 + d) = qv;
    float dx = qv.x - xs[r][d],     dy = qv.y - xs[r][d + 1];
    float dz = qv.z - xs[r][d + 2], dw = qv.w - xs[r][d + 3];
    csum += dx * dx + dy * dy + dz * dz + dw * dw;
  }
  #pragma unroll
  for (int off = 32; off; off >>= 1) csum += __shfl_xor(csum, off);
  if (lane == 0) cred[wv] = csum;
  __syncthreads();
  if (tid == 0) pc[blockIdx.x] = cred[0] + cred[1] + cred[2] + cred[3];
}

// ---------------------------------------------------------------------------
// recon |diff| partial reduce: 256 blocks over 524288 elems
// ---------------------------------------------------------------------------
__global__ __launch_bounds__(256) void absdiff_part_k(
    const float* __restrict__ a, const float* __restrict__ b, float* __restrict__ pr)
{
  __shared__ float cred[4];
  const int tid  = threadIdx.x;
  const int base = blockIdx.x * 2048;
  float s = 0.0f;
  for (int i = tid * 4; i < 2048; i += 1024) {
    float4 x = *(const float4*)(a + base + i);
    float4 y = *(const float4*)(b + base + i);
    s += fabsf(x.x - y.x) + fabsf(x.y - y.y) + fabsf(x.z - y.z) + fabsf(x.w - y.w);
  }
  #pragma unroll
  for (int off = 32; off; off >>= 1) s += __shfl_xor(s, off);
  const int lane = tid & 63, wv = tid >> 6;
  if (lane == 0) cred[wv] = s;
  __syncthreads();
  if (tid == 0) pr[blockIdx.x] = cred[0] + cred[1] + cred[2] + cred[3];
}

// ---------------------------------------------------------------------------
// Final scalar losses (single block, deterministic)
// ---------------------------------------------------------------------------
__global__ __launch_bounds__(256) void finalize_k(
    const float* __restrict__ pc, const float* __restrict__ pr, float* __restrict__ outp)
{
  __shared__ float red[4];
  const int tid = threadIdx.x;
  const int lane = tid & 63, wv = tid >> 6;

  float s = 0.0f;
  for (int i = tid; i < 8192; i += 256) s += pc[i];
  #pragma unroll
  for (int off = 32; off; off >>= 1) s += __shfl_xor(s, off);
  if (lane == 0) red[wv] = s;
  __syncthreads();
  if (tid == 0) outp[0] = 0.25f * (red[0] + red[1] + red[2] + red[3]) / 33554432.0f;
  __syncthreads();

  float s2 = 0.0f;
  if (tid < 64) {
    for (int i = tid; i < 256; i += 64) s2 += pr[i];
    #pragma unroll
    for (int off = 32; off; off >>= 1) s2 += __shfl_xor(s2, off);
    if (tid == 0) outp[1] = s2 / 524288.0f;
  }
}

// ---------------------------------------------------------------------------
extern "C" void kernel_launch(void* const* d_in, const int* in_sizes, int n_in,
                              void* d_out, int out_size, void* d_ws, size_t ws_size,
                              hipStream_t stream) {
  const float* wave = (const float*)d_in[0];
  const float* e1w = (const float*)d_in[1];  const float* e1b = (const float*)d_in[2];
  const float* e2w = (const float*)d_in[3];  const float* e2b = (const float*)d_in[4];
  const float* e3w = (const float*)d_in[5];  const float* e3b = (const float*)d_in[6];
  const float* e4w = (const float*)d_in[7];  const float* e4b = (const float*)d_in[8];
  const float* e5w = (const float*)d_in[9];  const float* e5b = (const float*)d_in[10];
  const float* cb  = (const float*)d_in[11];
  const float* d1w = (const float*)d_in[12]; const float* d1b = (const float*)d_in[13];
  const float* d2w = (const float*)d_in[14]; const float* d2b = (const float*)d_in[15];
  const float* d3w = (const float*)d_in[16]; const float* d3b = (const float*)d_in[17];
  const float* d4w = (const float*)d_in[18]; const float* d4b = (const float*)d_in[19];
  const float* d5w = (const float*)d_in[20]; const float* d5b = (const float*)d_in[21];

  float* out = (float*)d_out;
  float* recon  = out;                   // (8, 65536)
  float* qout   = out + 524288;          // (8, 8192, 512)
  float* codes  = out + 34078720;        // (8, 8192) as float
  float* losses = out + 34144256;        // [commitment, recon]

  float* A   = (float*)d_ws;             // 33554432 floats
  float* Bb  = A + 33554432;             // 33554432 floats
  float* t1  = Bb + 33554432;            // 65536
  float* cn  = t1 + 65536;               // 1024
  float* pc  = cn + 1024;                // 8192
  float* pr  = pc + 8192;                // 256

  dim3 blk(256);

  // ---- encoder (f32, numpy-faithful; 16 co per block) ----
  conv1d_k<15,1,7,1><<<dim3(128,  4, 8), blk, 0, stream>>>(wave, e1w, e1b, A,   1,  64, 65536, 65536);
  conv1d_k<15,2,7,1><<<dim3( 64,  8, 8), blk, 0, stream>>>(A,    e2w, e2b, Bb, 64, 128, 65536, 32768);
  conv1d_k<15,2,7,1><<<dim3( 32, 16, 8), blk, 0, stream>>>(Bb,   e3w, e3b, A, 128, 256, 32768, 16384);
  conv1d_k<15,2,7,1><<<dim3( 16, 32, 8), blk, 0, stream>>>(A,    e4w, e4b, Bb,256, 512, 16384,  8192);
  conv1d_k< 7,1,3,0><<<dim3( 16, 32, 8), blk, 0, stream>>>(Bb,   e5w, e5b, A, 512, 512,  8192,  8192);

  // ---- VQ (f32 numpy expression) ----
  transpose_k<<<dim3(256, 16, 8), dim3(32, 8), 0, stream>>>(A, Bb, 512, 8192);   // emb -> embT (B,T,D)
  rowsumsq_k<<<dim3(256), blk, 0, stream>>>(Bb, t1, 65536);
  rowsumsq_k<<<dim3(4),   blk, 0, stream>>>(cb, cn, 1024);
  vq_k<<<dim3(8192), blk, 0, stream>>>(Bb, cb, t1, cn, qout, codes, pc);
  transpose_k<<<dim3(16, 256, 8), dim3(32, 8), 0, stream>>>(qout, A, 8192, 512); // q -> (B,D,T)

  // ---- decoder (f32; 16 co per block) ----
  convt1d_k< 7,1,3,1><<<dim3( 16, 32, 8), blk, 0, stream>>>(A,  d1w, d1b, Bb, 512, 512,  8192,  8192);
  convt1d_k<15,2,7,1><<<dim3( 32, 16, 8), blk, 0, stream>>>(Bb, d2w, d2b, A,  512, 256,  8192, 16384);
  convt1d_k<15,2,7,1><<<dim3( 64,  8, 8), blk, 0, stream>>>(A,  d3w, d3b, Bb, 256, 128, 16384, 32768);
  convt1d_k<15,2,7,1><<<dim3(128,  4, 8), blk, 0, stream>>>(Bb, d4w, d4b, A,  128,  64, 32768, 65536);
  convt_final_k<<<dim3(32, 1, 8), blk, 0, stream>>>(A, d5w, d5b, recon);

  // ---- losses ----
  absdiff_part_k<<<dim3(256), blk, 0, stream>>>(recon, wave, pr);
  finalize_k<<<dim3(1), blk, 0, stream>>>(pc, pr, losses);
}

// Round 6
// 20509.837 us; speedup vs baseline: 2.3034x; 1.1877x over previous
//
#include <hip/hip_runtime.h>
#include <hip/hip_bf16.h>
#include <math.h>

#define DEV __device__ __forceinline__

typedef __attribute__((ext_vector_type(8))) short s16x8;   // 8 bf16 in 4 VGPRs
typedef __attribute__((ext_vector_type(4))) float f32x4;

// ELU matching numpy (encoder only): f64 expm1 + single f32 round.
DEV float elu_f(float v) { return v > 0.0f ? v : (float)expm1((double)v); }
// fast f32 ELU (decoder epilogue; accuracy uncritical)
DEV float elu_fast(float v) { return v > 0.0f ? v : expm1f(v); }

DEV unsigned short f2bf(float f) {
  unsigned u = __float_as_uint(f);
  return (unsigned short)((u + 0x7fffu + ((u >> 16) & 1u)) >> 16);
}
DEV float bf2f(unsigned short s) { return __uint_as_float(((unsigned)s) << 16); }

constexpr int ceil_div_c(int a, int b) { return (a > 0) ? (a + b - 1) / b : -((-a) / b); }

// ---------------------------------------------------------------------------
// f32 forward conv1d, numpy/BLAS-faithful accumulation (encoder — BIT-EXACT,
// do not change the per-output (ci outer, k inner) sequential FMA chain).
// block = 256 = 4 waves; wave -> 4 co (16 co/block); thread -> 8 outputs.
// ---------------------------------------------------------------------------
template<int K, int S, int PAD, int ACT>
__global__ __launch_bounds__(256) void conv1d_k(
    const float* __restrict__ x, const float* __restrict__ w,
    const float* __restrict__ bias, float* __restrict__ y,
    int Cin, int Cout, int Lin, int Lout)
{
  constexpr int PT = 8;
  constexpr int W  = (PT - 1) * S + K;
  constexpr int M0 = (4 - (PAD & 3)) & 3;
  constexpr int NQ = (M0 + W + 3) / 4;
  constexpr int CC = 16;
  constexpr int KP = (K + 3) & ~3;

  const int lane = threadIdx.x & 63;
  const int wv   = threadIdx.x >> 6;
  const int b    = blockIdx.z;
  const int cob  = blockIdx.y * 16;
  const int t0   = (blockIdx.x * 64 + lane) * PT;

  __shared__ __align__(16) float wl[16][CC][KP];

  float acc[4][PT];
  #pragma unroll
  for (int cc = 0; cc < 4; ++cc)
    #pragma unroll
    for (int g = 0; g < PT; ++g) acc[cc][g] = 0.0f;

  const float* xb  = x + (size_t)b * Cin * Lin;
  const int start = t0 * S - PAD;
  const int vbase = start - M0;
  const bool fast = (vbase >= 0) && (vbase + 4 * NQ <= Lin);

  for (int c0 = 0; c0 < Cin; c0 += CC) {
    const int cn = (Cin - c0 < CC) ? (Cin - c0) : CC;
    __syncthreads();
    for (int i = threadIdx.x; i < 16 * cn * K; i += 256) {
      int cc  = i / (cn * K);
      int rem = i - cc * (cn * K);
      int ci  = rem / K;
      int k   = rem - ci * K;
      wl[cc][ci][k] = w[((size_t)(cob + cc) * Cin + (c0 + ci)) * K + k];
    }
    __syncthreads();
    #pragma unroll 1
    for (int ci = 0; ci < cn; ++ci) {
      const float* xp = xb + (size_t)(c0 + ci) * Lin;
      float xr[W];
      if (fast) {
        float4 q[NQ];
        const float4* qp = (const float4*)(xp + vbase);
        #pragma unroll
        for (int j = 0; j < NQ; ++j) q[j] = qp[j];
        #pragma unroll
        for (int j = 0; j < W; ++j) xr[j] = ((const float*)q)[M0 + j];
      } else {
        #pragma unroll
        for (int j = 0; j < W; ++j) {
          int ix = start + j;
          xr[j] = (ix >= 0 && ix < Lin) ? xp[ix] : 0.0f;
        }
      }
      #pragma unroll
      for (int cc = 0; cc < 4; ++cc) {
        float wk[KP];
        const float4* wq = (const float4*)(&wl[wv * 4 + cc][ci][0]);
        #pragma unroll
        for (int q4 = 0; q4 < KP / 4; ++q4) {
          float4 t = wq[q4];
          wk[q4*4+0] = t.x; wk[q4*4+1] = t.y; wk[q4*4+2] = t.z; wk[q4*4+3] = t.w;
        }
        #pragma unroll
        for (int k = 0; k < K; ++k) {
          const float wv_ = wk[k];
          #pragma unroll
          for (int g = 0; g < PT; ++g)
            acc[cc][g] = fmaf(wv_, xr[g * S + k], acc[cc][g]);
        }
      }
    }
  }

  #pragma unroll
  for (int cc = 0; cc < 4; ++cc) {
    const int co = cob + wv * 4 + cc;
    const float bv = bias[co];
    float res[PT];
    #pragma unroll
    for (int g = 0; g < PT; ++g) {
      float v = acc[cc][g] + bv;
      if (ACT == 1) v = elu_f(v);
      res[g] = v;
    }
    float* yp = y + ((size_t)b * Cout + co) * Lout + t0;
    *(float4*)(yp)     = make_float4(res[0], res[1], res[2], res[3]);
    *(float4*)(yp + 4) = make_float4(res[4], res[5], res[6], res[7]);
  }
}

// ---------------------------------------------------------------------------
// Batched 2D transpose: in (B, R, S) -> out (B, S, R).
// ---------------------------------------------------------------------------
__global__ __launch_bounds__(256) void transpose_k(
    const float* __restrict__ in, float* __restrict__ out, int R, int S_)
{
  __shared__ float tile[32][33];
  const int b  = blockIdx.z;
  const int r0 = blockIdx.y * 32;
  const int s0 = blockIdx.x * 32;
  const float* ib = in + (size_t)b * R * S_;
  float* ob = out + (size_t)b * R * S_;
  const int tx = threadIdx.x, ty = threadIdx.y;
  #pragma unroll
  for (int i = 0; i < 32; i += 8)
    tile[ty + i][tx] = ib[(size_t)(r0 + ty + i) * S_ + s0 + tx];
  __syncthreads();
  #pragma unroll
  for (int i = 0; i < 32; i += 8)
    ob[(size_t)(s0 + ty + i) * R + r0 + tx] = tile[tx][ty + i];
}

// ---------------------------------------------------------------------------
// numpy-pairwise-identical f32 sum of squares over 512 contiguous floats.
// ---------------------------------------------------------------------------
DEV float np_sumsq_128(const float* a) {
  float r[8];
  #pragma unroll
  for (int j = 0; j < 8; ++j) r[j] = __fmul_rn(a[j], a[j]);
  #pragma unroll
  for (int i = 8; i < 128; i += 8) {
    #pragma unroll
    for (int j = 0; j < 8; ++j)
      r[j] = __fadd_rn(r[j], __fmul_rn(a[i + j], a[i + j]));
  }
  float s01 = __fadd_rn(r[0], r[1]), s23 = __fadd_rn(r[2], r[3]);
  float s45 = __fadd_rn(r[4], r[5]), s67 = __fadd_rn(r[6], r[7]);
  return __fadd_rn(__fadd_rn(s01, s23), __fadd_rn(s45, s67));
}
DEV float np_sumsq_512(const float* a) {
  float s0 = np_sumsq_128(a);
  float s1 = np_sumsq_128(a + 128);
  float s2 = np_sumsq_128(a + 256);
  float s3 = np_sumsq_128(a + 384);
  return __fadd_rn(__fadd_rn(s0, s1), __fadd_rn(s2, s3));
}

__global__ __launch_bounds__(256) void rowsumsq_k(
    const float* __restrict__ in, float* __restrict__ out, int nrows)
{
  const int r = blockIdx.x * 256 + threadIdx.x;
  if (r >= nrows) return;
  out[r] = np_sumsq_512(in + (size_t)r * 512);
}

// ---------------------------------------------------------------------------
// VQ, numpy-f32-faithful (BIT-EXACT — do not change).
// ---------------------------------------------------------------------------
__global__ __launch_bounds__(256) void vq_k(
    const float* __restrict__ embT, const float* __restrict__ cb,
    const float* __restrict__ t1, const float* __restrict__ cnorm,
    float* __restrict__ qout, float* __restrict__ codes, float* __restrict__ pc)
{
  __shared__ __align__(16) float xs[8][512];
  __shared__ float rv[4][8];
  __shared__ int   ri[4][8];
  __shared__ int   bidx[8];
  __shared__ float cred[4];

  const int tid  = threadIdx.x;
  const int row0 = blockIdx.x * 8;

  for (int i = tid * 4; i < 4096; i += 1024)
    *(float4*)((float*)xs + i) = *(const float4*)(embT + (size_t)row0 * 512 + i);
  __syncthreads();

  float acc[4][8];
  #pragma unroll
  for (int j = 0; j < 4; ++j)
    #pragma unroll
    for (int r = 0; r < 8; ++r) acc[j][r] = 0.0f;

  const float* cbp = cb + (size_t)tid * 512;
  #pragma unroll 1
  for (int d0 = 0; d0 < 512; d0 += 4) {
    float4 xv[8];
    #pragma unroll
    for (int r = 0; r < 8; ++r) xv[r] = *(const float4*)&xs[r][d0];
    #pragma unroll
    for (int j = 0; j < 4; ++j) {
      float4 cv = *(const float4*)(cbp + (size_t)j * 256 * 512 + d0);
      #pragma unroll
      for (int r = 0; r < 8; ++r) {
        acc[j][r] = fmaf(cv.x, xv[r].x, acc[j][r]);
        acc[j][r] = fmaf(cv.y, xv[r].y, acc[j][r]);
        acc[j][r] = fmaf(cv.z, xv[r].z, acc[j][r]);
        acc[j][r] = fmaf(cv.w, xv[r].w, acc[j][r]);
      }
    }
  }

  float cnj[4];
  #pragma unroll
  for (int j = 0; j < 4; ++j) cnj[j] = cnorm[tid + 256 * j];
  float t1r[8];
  #pragma unroll
  for (int r = 0; r < 8; ++r) t1r[r] = t1[row0 + r];

  const int lane = tid & 63, wv = tid >> 6;
  #pragma unroll 1
  for (int r = 0; r < 8; ++r) {
    float bv = 0.0f; int bi = 0;
    #pragma unroll
    for (int j = 0; j < 4; ++j) {
      float dv = __fsub_rn(__fadd_rn(t1r[r], cnj[j]), __fmul_rn(2.0f, acc[j][r]));
      int ki = tid + 256 * j;
      if (j == 0 || dv < bv || (dv == bv && ki < bi)) { bv = dv; bi = ki; }
    }
    #pragma unroll
    for (int off = 32; off; off >>= 1) {
      float ov = __shfl_xor(bv, off);
      int   oi = __shfl_xor(bi, off);
      if (ov < bv || (ov == bv && oi < bi)) { bv = ov; bi = oi; }
    }
    if (lane == 0) { rv[wv][r] = bv; ri[wv][r] = bi; }
  }
  __syncthreads();
  if (tid < 8) {
    float bv = rv[0][tid]; int bi = ri[0][tid];
    #pragma unroll
    for (int wq = 1; wq < 4; ++wq) {
      float ov = rv[wq][tid]; int oi = ri[wq][tid];
      if (ov < bv || (ov == bv && oi < bi)) { bv = ov; bi = oi; }
    }
    bidx[tid] = bi;
    codes[row0 + tid] = (float)bi;
  }
  __syncthreads();

  float csum = 0.0f;
  for (int i = tid * 4; i < 4096; i += 1024) {
    int r = i >> 9, d = i & 511;
    float4 qv = *(const float4*)(cb + (size_t)bidx[r] * 512 + d);
    *(float4*)(qout + (size_t)(row0 + r) * 512 + d) = qv;
    float dx = qv.x - xs[r][d],     dy = qv.y - xs[r][d + 1];
    float dz = qv.z - xs[r][d + 2], dw = qv.w - xs[r][d + 3];
    csum += dx * dx + dy * dy + dz * dz + dw * dw;
  }
  #pragma unroll
  for (int off = 32; off; off >>= 1) csum += __shfl_xor(csum, off);
  if (lane == 0) cred[wv] = csum;
  __syncthreads();
  if (tid == 0) pc[blockIdx.x] = cred[0] + cred[1] + cred[2] + cred[3];
}

// ---------------------------------------------------------------------------
// f32 -> bf16 elementwise (4/thread)
// ---------------------------------------------------------------------------
__global__ __launch_bounds__(256) void f32_to_bf16_k(
    const float* __restrict__ in, unsigned short* __restrict__ out, int n4)
{
  int i = blockIdx.x * 256 + threadIdx.x;
  if (i >= n4) return;
  float4 v = *(const float4*)(in + (size_t)i * 4);
  ushort4 o;
  o.x = f2bf(v.x); o.y = f2bf(v.y); o.z = f2bf(v.z); o.w = f2bf(v.w);
  *(ushort4*)(out + (size_t)i * 4) = o;
}

__global__ __launch_bounds__(256) void zero_zbuf_k(unsigned short* z) {
  z[blockIdx.x * 256 + threadIdx.x] = 0;
}

// ---------------------------------------------------------------------------
// Decoder weight prepack: w [Cin][Cout][K] f32 -> wp bf16 laid out so a B-frag
// for mfma_16x16x32 is a 16B contiguous load per lane:
//   wp[ ((jj*(Cin/32) + ci/32)*4 + (ci%32)/8) * (Cout*8) + co*8 + ci%8 ]
// tap m = m0 + ms*jj.
// ---------------------------------------------------------------------------
__global__ __launch_bounds__(256) void prepack_w_k(
    const float* __restrict__ w, unsigned short* __restrict__ wp,
    int Cin, int Cout, int K, int T, int m0, int ms)
{
  int id = blockIdx.x * 256 + threadIdx.x;
  int tot = T * Cin * Cout;
  if (id >= tot) return;
  int jj  = id / (Cin * Cout);
  int rem = id - jj * (Cin * Cout);
  int ci  = rem / Cout;
  int co  = rem - ci * Cout;
  int m   = m0 + ms * jj;
  float v = w[((size_t)ci * Cout + co) * K + m];
  size_t dst = ((size_t)((jj * (Cin >> 5) + (ci >> 5)) * 4 + ((ci & 31) >> 3))) * ((size_t)Cout * 8)
             + (size_t)co * 8 + (ci & 7);
  wp[dst] = f2bf(v);
}

// ---------------------------------------------------------------------------
// MFMA implicit-GEMM transposed-conv (one parity): bf16 in/out, f32 accum.
// x: [B][Lin][Cin] bf16 row-major.  y: [B][Lout][Cout] bf16.
// y[co, S*u+p] = elu( bias[co] + sum_jj sum_ci w_pack * x[u + OFF0 - jj, ci] )
// grid: (Lu/64, Cout/16, B); 4 waves/block, one 16x16 tile each.
// ---------------------------------------------------------------------------
__global__ __launch_bounds__(256) void mfma_convt_k(
    const unsigned short* __restrict__ xb, const unsigned short* __restrict__ wp,
    const float* __restrict__ bias, unsigned short* __restrict__ yb,
    const unsigned short* __restrict__ zbuf,
    int Cin, int Cout, int Lin, int Lout, int S, int p, int T, int OFF0)
{
  const int lane = threadIdx.x & 63;
  const int wv   = threadIdx.x >> 6;
  const int r    = lane & 15;          // A row / B col / C col
  const int g    = lane >> 4;          // k-group
  const int b    = blockIdx.z;
  const int u0   = blockIdx.x * 64 + wv * 16;
  const int co0  = blockIdx.y * 16;
  const int CB   = Cin >> 5;

  f32x4 acc = {0.f, 0.f, 0.f, 0.f};
  const unsigned short* xbb = xb + (size_t)b * Lin * Cin + g * 8;
  const unsigned short* zp  = zbuf + g * 8;
  const unsigned short* wpb = wp + (size_t)(co0 + r) * 8 + (size_t)g * Cout * 8;
  const size_t bstride = (size_t)4 * Cout * 8;   // per (jj*CB+cb) step

  const float bv = bias[co0 + r];

  #pragma unroll 1
  for (int jj = 0; jj < T; ++jj) {
    int u = u0 + r + OFF0 - jj;
    bool val = (u >= 0) && (u < Lin);
    const unsigned short* ap = val ? (xbb + (size_t)u * Cin) : zp;
    const unsigned short* bp = wpb + (size_t)jj * CB * bstride;
    #pragma unroll 2
    for (int cb = 0; cb < CB; ++cb) {
      s16x8 a  = *(const s16x8*)(ap + cb * 32);
      s16x8 bf = *(const s16x8*)(bp + (size_t)cb * bstride);
      acc = __builtin_amdgcn_mfma_f32_16x16x32_bf16(a, bf, acc, 0, 0, 0);
    }
  }

  // C/D layout: col = lane&15 (= co), row = (lane>>4)*4 + reg (= u in tile)
  #pragma unroll
  for (int reg = 0; reg < 4; ++reg) {
    int u  = u0 + g * 4 + reg;
    int o  = S * u + p;
    float v = elu_fast(acc[reg] + bv);
    yb[((size_t)b * Lout + o) * Cout + (co0 + r)] = f2bf(v);
  }
}

// ---------------------------------------------------------------------------
// Final decoder layer from bf16 row-major input [B][65536][64]:
// recon[b,o] = tanh(bias + sum_m sum_ci w[ci,0,m] * x[b, o+7-m, ci])
// ---------------------------------------------------------------------------
__global__ __launch_bounds__(256) void convt_final_bf16_k(
    const unsigned short* __restrict__ xb, const float* __restrict__ w,
    const float* __restrict__ bias, float* __restrict__ y)
{
  __shared__ float wl[64][16];
  for (int i = threadIdx.x; i < 64 * 15; i += 256) wl[i / 15][i % 15] = w[i];
  __syncthreads();
  const int b = blockIdx.y;
  const int o = blockIdx.x * 256 + threadIdx.x;
  float acc = 0.0f;
  #pragma unroll 1
  for (int m = 0; m < 15; ++m) {
    int i = o + 7 - m;
    if (i < 0 || i >= 65536) continue;
    const unsigned short* xp = xb + ((size_t)b * 65536 + i) * 64;
    #pragma unroll
    for (int c8 = 0; c8 < 8; ++c8) {
      s16x8 xv = *(const s16x8*)(xp + c8 * 8);
      #pragma unroll
      for (int k = 0; k < 8; ++k)
        acc = fmaf(wl[c8 * 8 + k][m], bf2f((unsigned short)xv[k]), acc);
    }
  }
  y[(size_t)b * 65536 + o] = tanhf(acc + bias[0]);
}

// ---------------------------------------------------------------------------
// recon |diff| partial reduce + final losses
// ---------------------------------------------------------------------------
__global__ __launch_bounds__(256) void absdiff_part_k(
    const float* __restrict__ a, const float* __restrict__ b, float* __restrict__ pr)
{
  __shared__ float cred[4];
  const int tid  = threadIdx.x;
  const int base = blockIdx.x * 2048;
  float s = 0.0f;
  for (int i = tid * 4; i < 2048; i += 1024) {
    float4 x = *(const float4*)(a + base + i);
    float4 y = *(const float4*)(b + base + i);
    s += fabsf(x.x - y.x) + fabsf(x.y - y.y) + fabsf(x.z - y.z) + fabsf(x.w - y.w);
  }
  #pragma unroll
  for (int off = 32; off; off >>= 1) s += __shfl_xor(s, off);
  const int lane = tid & 63, wv = tid >> 6;
  if (lane == 0) cred[wv] = s;
  __syncthreads();
  if (tid == 0) pr[blockIdx.x] = cred[0] + cred[1] + cred[2] + cred[3];
}

__global__ __launch_bounds__(256) void finalize_k(
    const float* __restrict__ pc, const float* __restrict__ pr, float* __restrict__ outp)
{
  __shared__ float red[4];
  const int tid = threadIdx.x;
  const int lane = tid & 63, wv = tid >> 6;

  float s = 0.0f;
  for (int i = tid; i < 8192; i += 256) s += pc[i];
  #pragma unroll
  for (int off = 32; off; off >>= 1) s += __shfl_xor(s, off);
  if (lane == 0) red[wv] = s;
  __syncthreads();
  if (tid == 0) outp[0] = 0.25f * (red[0] + red[1] + red[2] + red[3]) / 33554432.0f;
  __syncthreads();

  float s2 = 0.0f;
  if (tid < 64) {
    for (int i = tid; i < 256; i += 64) s2 += pr[i];
    #pragma unroll
    for (int off = 32; off; off >>= 1) s2 += __shfl_xor(s2, off);
    if (tid == 0) outp[1] = s2 / 524288.0f;
  }
}

// ---------------------------------------------------------------------------
extern "C" void kernel_launch(void* const* d_in, const int* in_sizes, int n_in,
                              void* d_out, int out_size, void* d_ws, size_t ws_size,
                              hipStream_t stream) {
  const float* wave = (const float*)d_in[0];
  const float* e1w = (const float*)d_in[1];  const float* e1b = (const float*)d_in[2];
  const float* e2w = (const float*)d_in[3];  const float* e2b = (const float*)d_in[4];
  const float* e3w = (const float*)d_in[5];  const float* e3b = (const float*)d_in[6];
  const float* e4w = (const float*)d_in[7];  const float* e4b = (const float*)d_in[8];
  const float* e5w = (const float*)d_in[9];  const float* e5b = (const float*)d_in[10];
  const float* cb  = (const float*)d_in[11];
  const float* d1w = (const float*)d_in[12]; const float* d1b = (const float*)d_in[13];
  const float* d2w = (const float*)d_in[14]; const float* d2b = (const float*)d_in[15];
  const float* d3w = (const float*)d_in[16]; const float* d3b = (const float*)d_in[17];
  const float* d4w = (const float*)d_in[18]; const float* d4b = (const float*)d_in[19];
  const float* d5w = (const float*)d_in[20]; const float* d5b = (const float*)d_in[21];

  float* out = (float*)d_out;
  float* recon  = out;                   // (8, 65536)
  float* qout   = out + 524288;          // (8, 8192, 512)
  float* codes  = out + 34078720;        // (8, 8192) as float
  float* losses = out + 34144256;        // [commitment, recon]

  float* A   = (float*)d_ws;             // 33554432 floats
  float* Bb  = A + 33554432;             // 33554432 floats
  float* t1  = Bb + 33554432;            // 65536
  float* cn  = t1 + 65536;               // 1024
  float* pc  = cn + 1024;                // 8192
  float* pr  = pc + 8192;                // 256

  // bf16 regions (reuse A/Bb halves; all dead/live windows verified):
  unsigned short* qb  = (unsigned short*)A;                    // 33.5M bf16 (A 1st half)
  unsigned short* yb1 = (unsigned short*)Bb;                   // d1 out (Bb 1st half)
  unsigned short* yb2 = (unsigned short*)A;                    // d2 out (A 1st half, qb dead)
  unsigned short* yb3 = (unsigned short*)(Bb + 16777216);      // d3 out (Bb 2nd half)
  unsigned short* yb4 = (unsigned short*)A;                    // d4 out (A 1st half, yb2 dead)
  // wp packs + zbuf in A's 2nd half (free after transpose, untouched by yb2/yb4)
  unsigned short* wsp   = (unsigned short*)(A + 16777216);
  unsigned short* zbuf  = wsp;                    // 1024
  unsigned short* wp1   = zbuf + 1024;            // 7*512*512   = 1,835,008
  unsigned short* wp2e  = wp1  + 1835008;         // 7*512*256   =   917,504
  unsigned short* wp2o  = wp2e + 917504;          // 8*512*256   = 1,048,576
  unsigned short* wp3e  = wp2o + 1048576;         // 7*256*128   =   229,376
  unsigned short* wp3o  = wp3e + 229376;          // 8*256*128   =   262,144
  unsigned short* wp4e  = wp3o + 262144;          // 7*128*64    =    57,344
  unsigned short* wp4o  = wp4e + 57344;           // 8*128*64    =    65,536

  dim3 blk(256);

  // ---- encoder (f32, numpy-faithful; BIT-EXACT) ----
  conv1d_k<15,1,7,1><<<dim3(128,  4, 8), blk, 0, stream>>>(wave, e1w, e1b, A,   1,  64, 65536, 65536);
  conv1d_k<15,2,7,1><<<dim3( 64,  8, 8), blk, 0, stream>>>(A,    e2w, e2b, Bb, 64, 128, 65536, 32768);
  conv1d_k<15,2,7,1><<<dim3( 32, 16, 8), blk, 0, stream>>>(Bb,   e3w, e3b, A, 128, 256, 32768, 16384);
  conv1d_k<15,2,7,1><<<dim3( 16, 32, 8), blk, 0, stream>>>(A,    e4w, e4b, Bb,256, 512, 16384,  8192);
  conv1d_k< 7,1,3,0><<<dim3( 16, 32, 8), blk, 0, stream>>>(Bb,   e5w, e5b, A, 512, 512,  8192,  8192);

  // ---- VQ (f32 numpy expression; BIT-EXACT) ----
  transpose_k<<<dim3(256, 16, 8), dim3(32, 8), 0, stream>>>(A, Bb, 512, 8192);   // emb -> embT
  rowsumsq_k<<<dim3(256), blk, 0, stream>>>(Bb, t1, 65536);
  rowsumsq_k<<<dim3(4),   blk, 0, stream>>>(cb, cn, 1024);
  vq_k<<<dim3(8192), blk, 0, stream>>>(Bb, cb, t1, cn, qout, codes, pc);

  // ---- decoder prep (A free now): q->bf16, zero stub row, weight packs ----
  f32_to_bf16_k<<<dim3(32768), blk, 0, stream>>>(qout, qb, 8388608);
  zero_zbuf_k<<<dim3(4), blk, 0, stream>>>(zbuf);
  prepack_w_k<<<dim3(7168), blk, 0, stream>>>(d1w, wp1, 512, 512, 7, 7, 0, 1);
  prepack_w_k<<<dim3(3584), blk, 0, stream>>>(d2w, wp2e, 512, 256, 15, 7, 1, 2);
  prepack_w_k<<<dim3(4096), blk, 0, stream>>>(d2w, wp2o, 512, 256, 15, 8, 0, 2);
  prepack_w_k<<<dim3( 896), blk, 0, stream>>>(d3w, wp3e, 256, 128, 15, 7, 1, 2);
  prepack_w_k<<<dim3(1024), blk, 0, stream>>>(d3w, wp3o, 256, 128, 15, 8, 0, 2);
  prepack_w_k<<<dim3( 224), blk, 0, stream>>>(d4w, wp4e, 128,  64, 15, 7, 1, 2);
  prepack_w_k<<<dim3( 256), blk, 0, stream>>>(d4w, wp4o, 128,  64, 15, 8, 0, 2);

  // ---- decoder (bf16 MFMA implicit GEMM) ----
  // d1: K7 S1 P3: off = 3 - jj
  mfma_convt_k<<<dim3(128, 32, 8), blk, 0, stream>>>(qb,  wp1,  d1b, yb1, zbuf, 512, 512, 8192, 8192, 1, 0, 7, 3);
  // d2: K15 S2 P7 (even: m=2jj+1, off=3-jj; odd: m=2jj, off=4-jj)
  mfma_convt_k<<<dim3(128, 16, 8), blk, 0, stream>>>(yb1, wp2e, d2b, yb2, zbuf, 512, 256, 8192, 16384, 2, 0, 7, 3);
  mfma_convt_k<<<dim3(128, 16, 8), blk, 0, stream>>>(yb1, wp2o, d2b, yb2, zbuf, 512, 256, 8192, 16384, 2, 1, 8, 4);
  // d3
  mfma_convt_k<<<dim3(256,  8, 8), blk, 0, stream>>>(yb2, wp3e, d3b, yb3, zbuf, 256, 128, 16384, 32768, 2, 0, 7, 3);
  mfma_convt_k<<<dim3(256,  8, 8), blk, 0, stream>>>(yb2, wp3o, d3b, yb3, zbuf, 256, 128, 16384, 32768, 2, 1, 8, 4);
  // d4
  mfma_convt_k<<<dim3(512,  4, 8), blk, 0, stream>>>(yb3, wp4e, d4b, yb4, zbuf, 128,  64, 32768, 65536, 2, 0, 7, 3);
  mfma_convt_k<<<dim3(512,  4, 8), blk, 0, stream>>>(yb3, wp4o, d4b, yb4, zbuf, 128,  64, 32768, 65536, 2, 1, 8, 4);
  // d5: tanh, f32 out
  convt_final_bf16_k<<<dim3(256, 8), blk, 0, stream>>>(yb4, d5w, d5b, recon);

  // ---- losses ----
  absdiff_part_k<<<dim3(256), blk, 0, stream>>>(recon, wave, pr);
  finalize_k<<<dim3(1), blk, 0, stream>>>(pc, pr, losses);
}